// Round 14
// baseline (3242.027 us; speedup 1.0000x reference)
//
#include <hip/hip_runtime.h>
#include <hip/hip_bf16.h>

// MaskedLSTM: B=128 S=1024 I=512 H=512
// out = [B,S,H] f32 ++ hT [1,B,H] f32 ++ cT [1,B,H] f32
//
// v14 = v13 (PASSED, recur 2.35ms: sleep16 + tagged single-sweep exchange) +
//  (1) recur: loop-end __syncthreads removed (redundant: af reads complete
//      before the comb barrier; next-iter stage/scatter gated by sync1/sync2).
//  (2) xgemm: B tiles staged via __builtin_amdgcn_global_load_lds width=16
//      (wave-uniform LDS base + lane*16; per-lane global src). B is bf16 and
//      2/3 of staged bytes; removes 8 ds_writes + VGPR round-trip per kb.
//  Protocol/timing in recur otherwise byte-identical to v13.
// Burned lessons: no __threadfence (R1), no flag/RMW barriers (R2/R7), no
// sc0/sc1 hand asm / block reorg (R3/R5), no serial dependent polling (R4),
// no 2x poll traffic (R8), no de-coalesced pulls (R10), no work-doubling or
// stagger pipelining (R11/R12 — zero overlap capturable at this RTT).

typedef __attribute__((ext_vector_type(8))) short short8;
typedef __attribute__((ext_vector_type(4))) float floatx4;
typedef unsigned short ushort_t;

static constexpr size_t kMat   = 512 * 512;
static constexpr size_t O_W    = 0;                      // 12 mats bf16
static constexpr size_t O_XGO  = 12 * kMat * 2;
static constexpr size_t O_XGC  = O_XGO + 134217728ull;
static constexpr size_t O_XGF  = O_XGC + 134217728ull;   // last-step xg_f (B*H bf16)
static constexpr size_t O_HB   = O_XGF + 131072ull;      // tagged h: [16 teams][2 ph][4096 u32]

__device__ __forceinline__ ushort_t f2bf(float f) {
  unsigned u = __float_as_uint(f);
  u = (u + 0x7FFFu + ((u >> 16) & 1u)) >> 16;
  return (ushort_t)u;
}
__device__ __forceinline__ float bf2f(ushort_t h) {
  return __uint_as_float(((unsigned)h) << 16);
}
__device__ __forceinline__ float sigf(float x) { return 1.0f / (1.0f + __expf(-x)); }
__device__ __forceinline__ float tanhfast(float x) { return 2.0f * sigf(2.0f * x) - 1.0f; }

struct Ptrs12 { const float* p[12]; };

// ---------------- prep: weights fp32->bf16, zero tagged h buffer ----------------
__global__ void k_prep(Ptrs12 a, ushort_t* __restrict__ wbf, unsigned* __restrict__ zr) {
  unsigned idx = blockIdx.x * 256u + threadIdx.x;
  const unsigned WTOT = 12u * 262144u;
  if (idx < WTOT) {
    wbf[idx] = f2bf(a.p[idx >> 18][idx & 262143u]);
  } else {
    zr[idx - WTOT] = 0u;   // zeroes all 131072 u32 of hbuf (tag 0 == step 0, h(0)=0)
  }
}

// ---------------- x-projection masked-linear GEMM ----------------
// grid (12, 1024): combo = (gate p, N-tile) fastest -> one A-tile's 12 readers
// dispatch consecutively (L2/L3-hot A), M-tile slowest. 128x128 tiles.
__global__ __launch_bounds__(256, 2) void k_xgemm(
    const float* __restrict__ x, const ushort_t* __restrict__ wbf,
    ushort_t* __restrict__ xgo, ushort_t* __restrict__ xgc,
    ushort_t* __restrict__ xgf_last, ushort_t* out_xgf) {
  __shared__ ushort_t At[128][64];
  __shared__ ushort_t Bt[2][128][64];
  const int combo = blockIdx.x;
  const int p  = combo % 3;
  const int n0 = (combo / 3) * 128;
  const int R0 = blockIdx.y * 128;
  const ushort_t* Wmain = wbf + (size_t)(2 * p) * kMat;
  const ushort_t* Wmask = wbf + (size_t)(2 * p + 1) * kMat;
  const int tid = threadIdx.x;
  const int lane = tid & 63, w = tid >> 6;
  const int wr = w >> 1, wc = w & 1;
  const int sr = tid >> 1, sh = tid & 1;

  floatx4 accM[4][4], accK[4][4];
#pragma unroll
  for (int mt = 0; mt < 4; ++mt)
#pragma unroll
    for (int nt = 0; nt < 4; ++nt) {
      accM[mt][nt] = (floatx4){0.f, 0.f, 0.f, 0.f};
      accK[mt][nt] = (floatx4){0.f, 0.f, 0.f, 0.f};
    }

  for (int kb = 0; kb < 8; ++kb) {
    __syncthreads();
    // ---- stage B via async global->LDS (width 16): wave w, call j stages
    //      8 rows r8=(j*4+w)*8; lane l -> row r8+(l>>3), col (l&7)*8 elems ----
#pragma unroll
    for (int m2 = 0; m2 < 2; ++m2) {
      const ushort_t* Wsrc = m2 ? Wmask : Wmain;
#pragma unroll
      for (int j = 0; j < 4; ++j) {
        const int r8 = (j * 4 + w) * 8;
        const ushort_t* g = Wsrc + (size_t)(n0 + r8 + (lane >> 3)) * 512 + kb * 64 + (lane & 7) * 8;
        __builtin_amdgcn_global_load_lds(
            (const __attribute__((address_space(1))) unsigned int*)g,
            (__attribute__((address_space(3))) unsigned int*)&Bt[m2][r8][0],
            16, 0, 0);
      }
    }
    // ---- stage A: x fp32 -> bf16 (register path; conversion required) ----
    const float* xa = x + (size_t)(R0 + sr) * 512 + kb * 64 + sh * 32;
#pragma unroll
    for (int q = 0; q < 4; ++q) {
      float4 v0 = *reinterpret_cast<const float4*>(xa + q * 8);
      float4 v1 = *reinterpret_cast<const float4*>(xa + q * 8 + 4);
      short8 s;
      s[0] = (short)f2bf(v0.x); s[1] = (short)f2bf(v0.y);
      s[2] = (short)f2bf(v0.z); s[3] = (short)f2bf(v0.w);
      s[4] = (short)f2bf(v1.x); s[5] = (short)f2bf(v1.y);
      s[6] = (short)f2bf(v1.z); s[7] = (short)f2bf(v1.w);
      *reinterpret_cast<short8*>(&At[sr][sh * 32 + q * 8]) = s;
    }
    __syncthreads();   // drains vmcnt (incl. global_load_lds) + lgkm before reads
#pragma unroll
    for (int ks = 0; ks < 2; ++ks) {
      const int ko = ks * 32 + (lane >> 4) * 8;
      short8 a[4], b0[4], b1[4];
#pragma unroll
      for (int mt = 0; mt < 4; ++mt)
        a[mt] = *reinterpret_cast<const short8*>(&At[wr * 64 + mt * 16 + (lane & 15)][ko]);
#pragma unroll
      for (int nt = 0; nt < 4; ++nt) {
        b0[nt] = *reinterpret_cast<const short8*>(&Bt[0][wc * 64 + nt * 16 + (lane & 15)][ko]);
        b1[nt] = *reinterpret_cast<const short8*>(&Bt[1][wc * 64 + nt * 16 + (lane & 15)][ko]);
      }
#pragma unroll
      for (int mt = 0; mt < 4; ++mt)
#pragma unroll
        for (int nt = 0; nt < 4; ++nt) {
          accM[mt][nt] = __builtin_amdgcn_mfma_f32_16x16x32_bf16(a[mt], b0[nt], accM[mt][nt], 0, 0, 0);
          accK[mt][nt] = __builtin_amdgcn_mfma_f32_16x16x32_bf16(a[mt], b1[nt], accK[mt][nt], 0, 0, 0);
        }
    }
  }
#pragma unroll
  for (int mt = 0; mt < 4; ++mt)
#pragma unroll
    for (int nt = 0; nt < 4; ++nt)
#pragma unroll
      for (int r = 0; r < 4; ++r) {
        float val = sigf(accK[mt][nt][r]) * accM[mt][nt][r];
        int row = R0 + wr * 64 + mt * 16 + (lane >> 4) * 4 + r;   // flattened b*S+t
        int col = n0 + wc * 64 + nt * 16 + (lane & 15);
        ushort_t bv = f2bf(val);
        if (p == 1) {
          xgo[(size_t)row * 512 + col] = bv;
        } else if (p == 2) {
          xgc[(size_t)row * 512 + col] = bv;
        } else {
          int t = row & 1023;
          if (t == 1023) xgf_last[(row >> 10) * 512 + col] = bv;
          else out_xgf[(size_t)(row + 1) * 1024 + 512 + col] = bv;  // upper half of f32 slot t+1
        }
      }
}

// ---------------- recurrence: persistent, 16 teams x 16 blocks, tagged exchange ----------------
__global__ __launch_bounds__(256, 1) void k_recur(
    const ushort_t* __restrict__ ubf,
    const ushort_t* __restrict__ xgo, const ushort_t* __restrict__ xgc,
    const ushort_t* __restrict__ xgf_last,
    unsigned* hbuf,
    const float* __restrict__ bfp, const float* __restrict__ bop, const float* __restrict__ bcp,
    float* out) {
  __shared__ ushort_t htile[16][520];   // rows 8..15 stay zero
  __shared__ float comb[12][8][16];
  const int bid = blockIdx.x;
  const int team = bid >> 4;     // 16 teams of 8 batch rows
  const int member = bid & 15;   // 16 blocks/team, 32 cols each
  const int tid = threadIdx.x;
  const int lane = tid & 63, w = tid >> 6;

  // ---- resident U weight fragments: wave w owns chunks {w, w+4, w+8} ----
  short8 uw[3][16];
#pragma unroll
  for (int i = 0; i < 3; ++i) {
    const int c = w + 4 * i;
    const int m = c % 6, ct = c / 6;
    const int row = member * 32 + ct * 16 + (lane & 15);
    const ushort_t* src = ubf + (size_t)m * kMat + (size_t)row * 512 + (lane >> 4) * 8;
#pragma unroll
    for (int kf = 0; kf < 16; ++kf)
      uw[i][kf] = *reinterpret_cast<const short8*>(src + kf * 32);
  }
  // keep weight values non-rematerializable (R8/R9 insurance)
#pragma unroll
  for (int i = 0; i < 3; ++i)
#pragma unroll
    for (int kf = 0; kf < 16; ++kf)
      asm volatile("" : "+v"(uw[i][kf]));

  // zero htile rows 8..15 and the pad columns once
  {
    unsigned* hrow = reinterpret_cast<unsigned*>(&htile[8 + (tid >> 5)][0]) + (tid & 31) * 8;
#pragma unroll
    for (int q = 0; q < 8; ++q) hrow[q] = 0u;
    if (tid < 64) {
      reinterpret_cast<unsigned*>(&htile[tid >> 2][512])[tid & 3] = 0u;
    }
  }

  // elementwise identity: thread -> (row er, col ej)
  const int er = tid >> 5;          // 0..7
  const int ej = tid & 31;          // 0..31
  const int ect = ej >> 4, ejj = ej & 15;
  const int col = member * 32 + ej;
  const int b = team * 8 + er;
  const float bfv = bfp[col], bov = bop[col], bcv = bcp[col];
  float cp = 0.0f;

  unsigned* hb = hbuf + (size_t)team * 8192;   // [2 phases][4096] tagged words
  const ushort_t* out_us = reinterpret_cast<const ushort_t*>(out);

  for (int t = 0; t < 1024; ++t) {
    // xg prefetch (independent of h; in flight during the sleep + poll)
    const size_t bt = (size_t)b * 1024 + t;
    const float xov = bf2f(xgo[bt * 512 + col]);
    const float xcv = bf2f(xgc[bt * 512 + col]);
    const float xfv = (t == 1023) ? bf2f(xgf_last[b * 512 + col])
                                  : bf2f(out_us[(bt + 1) * 1024 + 512 + col]);

    // ---- poll + pull h(t): 16 tagged words/thread, single rolling sweep ----
    {
      const unsigned tg = (unsigned)t & 0xFFFFu;
      const unsigned* src = hb + (size_t)(t & 1) * 4096 + tid;
      unsigned wv[16];
      // sleep ~1kcy: matches publish-store one-way commit latency (R13 win)
      if (t) __builtin_amdgcn_s_sleep(16);
#pragma unroll
      for (int q = 0; q < 16; ++q)
        wv[q] = __hip_atomic_load(src + q * 256, __ATOMIC_RELAXED, __HIP_MEMORY_SCOPE_AGENT);
      for (;;) {
        unsigned bad = 0u;
#pragma unroll
        for (int q = 0; q < 16; ++q) bad |= (wv[q] ^ tg);
        if ((bad & 0xFFFFu) == 0u) break;
        // batched re-load of stale words only (exec-masked, all outstanding together)
#pragma unroll
        for (int q = 0; q < 16; ++q)
          if ((wv[q] & 0xFFFFu) != tg)
            wv[q] = __hip_atomic_load(src + q * 256, __ATOMIC_RELAXED, __HIP_MEMORY_SCOPE_AGENT);
      }
      // stage to LDS: word (q*256+tid) -> row q>>1, col (q&1)*256+tid
#pragma unroll
      for (int q = 0; q < 16; ++q)
        htile[q >> 1][(q & 1) * 256 + tid] = (ushort_t)(wv[q] >> 16);
    }
    __syncthreads();

    // ---- A fragments from LDS ----
    short8 af[16];
    {
      const ushort_t* abase = &htile[lane & 15][(lane >> 4) * 8];
#pragma unroll
      for (int kf = 0; kf < 16; ++kf)
        af[kf] = *reinterpret_cast<const short8*>(abase + kf * 32);
    }

    floatx4 acc[3];
#pragma unroll
    for (int i = 0; i < 3; ++i) acc[i] = (floatx4){0.f, 0.f, 0.f, 0.f};
#pragma unroll
    for (int kf = 0; kf < 16; ++kf)
#pragma unroll
      for (int i = 0; i < 3; ++i)
        acc[i] = __builtin_amdgcn_mfma_f32_16x16x32_bf16(af[kf], uw[i][kf], acc[i], 0, 0, 0);

    // scatter acc rows 0..7 to LDS for the pair-combine
    if (lane < 32) {
      const int rr = (lane >> 4) * 4;
#pragma unroll
      for (int i = 0; i < 3; ++i) {
        const int c = w + 4 * i;
#pragma unroll
        for (int r = 0; r < 4; ++r) comb[c][rr + r][lane & 15] = acc[i][r];
      }
    }
    __syncthreads();

    const float hUf  = comb[ect * 6 + 0][er][ejj];
    const float hUfm = comb[ect * 6 + 1][er][ejj];
    const float hUo  = comb[ect * 6 + 2][er][ejj];
    const float hUom = comb[ect * 6 + 3][er][ejj];
    const float hUc  = comb[ect * 6 + 4][er][ejj];
    const float hUcm = comb[ect * 6 + 5][er][ejj];

    const float fg = sigf(sigf(hUfm) * hUf + xfv + bfv);
    const float og = sigf(sigf(hUom) * hUo + xov + bov);
    const float cn = fg * cp + tanhfast(sigf(hUcm) * hUc + xcv + bcv);
    const float hv = og * cn;
    cp = cn;

    // ---- publish h(t+1) first (starts propagating while we finish stores) ----
    if (t < 1023) {
      const unsigned word = ((unsigned)f2bf(hv) << 16) | ((unsigned)(t + 1) & 0xFFFFu);
      __hip_atomic_store(hb + (size_t)((t + 1) & 1) * 4096 + er * 512 + col, word,
                         __ATOMIC_RELAXED, __HIP_MEMORY_SCOPE_AGENT);
    }

    out[bt * 512 + col] = hv;                       // y (overwrites consumed xg_f slot)
    if (t == 1023) {
      out[67108864ull + (size_t)b * 512 + col] = hv;            // hT
      out[67108864ull + 65536ull + (size_t)b * 512 + col] = cn; // cT
    }
    // NOTE: no loop-end barrier. Safety: af reads complete before the comb
    // barrier (program order: af -> scatter -> sync2), so next-iter htile
    // staging (post-sync2) can't race them; next-iter comb scatter is gated
    // by next sync1, which every thread reaches only after its comb reads.
  }
}

extern "C" void kernel_launch(void* const* d_in, const int* in_sizes, int n_in,
                              void* d_out, int out_size, void* d_ws, size_t ws_size,
                              hipStream_t stream) {
  (void)in_sizes; (void)n_in; (void)out_size; (void)ws_size;
  // d_in order: 0 Wf,1 Wf_m,2 Wi,3 Wi_m,4 Wo,5 Wo_m,6 Wc,7 Wc_m,
  //             8 Uf,9 Uf_m,10 Ui,11 Ui_m,12 Uo,13 Uo_m,14 Uc,15 Uc_m,
  //             16 bf,17 bi,18 bo,19 bc, 20 x
  char* ws = (char*)d_ws;
  ushort_t* wbf = (ushort_t*)(ws + O_W);
  const ushort_t* ubf = wbf + 6 * kMat;
  ushort_t* xgo = (ushort_t*)(ws + O_XGO);
  ushort_t* xgc = (ushort_t*)(ws + O_XGC);
  ushort_t* xgfl = (ushort_t*)(ws + O_XGF);
  unsigned* hbuf = (unsigned*)(ws + O_HB);

  Ptrs12 pa;
  pa.p[0] = (const float*)d_in[0];  pa.p[1] = (const float*)d_in[1];   // Wf, Wf_m
  pa.p[2] = (const float*)d_in[4];  pa.p[3] = (const float*)d_in[5];   // Wo, Wo_m
  pa.p[4] = (const float*)d_in[6];  pa.p[5] = (const float*)d_in[7];   // Wc, Wc_m
  pa.p[6] = (const float*)d_in[8];  pa.p[7] = (const float*)d_in[9];   // Uf, Uf_m
  pa.p[8] = (const float*)d_in[12]; pa.p[9] = (const float*)d_in[13];  // Uo, Uo_m
  pa.p[10] = (const float*)d_in[14]; pa.p[11] = (const float*)d_in[15]; // Uc, Uc_m

  // zero exactly hbuf's 131072 u32 after converting 3145728 weight elems
  hipLaunchKernelGGL(k_prep, dim3((12u * 262144u + 131072u) / 256u), dim3(256), 0, stream,
                     pa, wbf, hbuf);
  hipLaunchKernelGGL(k_xgemm, dim3(12, 1024), dim3(256), 0, stream,
                     (const float*)d_in[20], wbf, xgo, xgc, xgfl, (ushort_t*)d_out);

  const ushort_t* a_ubf = ubf;
  const ushort_t* a_xgo = xgo;
  const ushort_t* a_xgc = xgc;
  const ushort_t* a_xgfl = xgfl;
  unsigned* a_hbuf = hbuf;
  const float* a_bf = (const float*)d_in[16];
  const float* a_bo = (const float*)d_in[18];
  const float* a_bc = (const float*)d_in[19];
  float* a_out = (float*)d_out;
  void* kargs[9] = { (void*)&a_ubf, (void*)&a_xgo, (void*)&a_xgc, (void*)&a_xgfl,
                     (void*)&a_hbuf, (void*)&a_bf, (void*)&a_bo, (void*)&a_bc, (void*)&a_out };
  hipError_t ce = hipLaunchCooperativeKernel((const void*)k_recur, dim3(256), dim3(256),
                                             kargs, 0, stream);
  if (ce != hipSuccess) {
    // fallback: plain launch (256 blocks, 1 block/CU, all co-resident)
    hipLaunchKernelGGL(k_recur, dim3(256), dim3(256), 0, stream,
                       ubf, xgo, xgc, xgfl, hbuf, a_bf, a_bo, a_bc, a_out);
  }
}

// Round 15
// 2956.093 us; speedup vs baseline: 1.0967x; 1.0967x over previous
//
#include <hip/hip_runtime.h>
#include <hip/hip_bf16.h>

// MaskedLSTM: B=128 S=1024 I=512 H=512
// out = [B,S,H] f32 ++ hT [1,B,H] f32 ++ cT [1,B,H] f32
//
// v15 = v13 recur EXACT (best: 2.35ms) + xgemm with zero-VALU staging:
//  - NEW k_conv: x fp32 -> bf16 ONCE, stored in d_out slot lower-halves
//    (slot s ushorts [0,512) = x_bf16(row s-1); xg_f lives in [512,1024) of
//    slot row+1 — byte-disjoint, line-disjoint, consumed before recur
//    overwrites). v14 finding: B-only global_load_lds was null because the
//    A-path (fp32 load + 12x-redundant f2bf + ds_write per combo) dominates.
//  - xgemm stages BOTH A and B via __builtin_amdgcn_global_load_lds w=16.
// Burned lessons: no __threadfence (R1), no flag/RMW barriers (R2/R7), no
// sc0/sc1 hand asm / block reorg (R3/R5), no serial dependent polling (R4),
// no 2x poll traffic (R8), no de-coalesced pulls (R10), no work-doubling or
// stagger pipelining (R11/R12), recur loop-end barrier stays (R14: removal
// not a win).

typedef __attribute__((ext_vector_type(8))) short short8;
typedef __attribute__((ext_vector_type(4))) float floatx4;
typedef unsigned short ushort_t;

static constexpr size_t kMat   = 512 * 512;
static constexpr size_t O_W    = 0;                      // 12 mats bf16
static constexpr size_t O_XGO  = 12 * kMat * 2;
static constexpr size_t O_XGC  = O_XGO + 134217728ull;
static constexpr size_t O_XGF  = O_XGC + 134217728ull;   // last-step xg_f (B*H bf16)
static constexpr size_t O_HB   = O_XGF + 131072ull;      // tagged h: [16 teams][2 ph][4096 u32]

__device__ __forceinline__ ushort_t f2bf(float f) {
  unsigned u = __float_as_uint(f);
  u = (u + 0x7FFFu + ((u >> 16) & 1u)) >> 16;
  return (ushort_t)u;
}
__device__ __forceinline__ float bf2f(ushort_t h) {
  return __uint_as_float(((unsigned)h) << 16);
}
__device__ __forceinline__ float sigf(float x) { return 1.0f / (1.0f + __expf(-x)); }
__device__ __forceinline__ float tanhfast(float x) { return 2.0f * sigf(2.0f * x) - 1.0f; }

struct Ptrs12 { const float* p[12]; };

// ---------------- prep: weights fp32->bf16, zero tagged h buffer ----------------
__global__ void k_prep(Ptrs12 a, ushort_t* __restrict__ wbf, unsigned* __restrict__ zr) {
  unsigned idx = blockIdx.x * 256u + threadIdx.x;
  const unsigned WTOT = 12u * 262144u;
  if (idx < WTOT) {
    wbf[idx] = f2bf(a.p[idx >> 18][idx & 262143u]);
  } else {
    zr[idx - WTOT] = 0u;   // zeroes all 131072 u32 of hbuf (tag 0 == step 0, h(0)=0)
  }
}

// ---------------- conv: x fp32 -> bf16 into d_out slot lower-halves ----------------
// x row r (flattened b*S+t) -> out ushorts [(r+1)*1024, (r+1)*1024+512)
__global__ void k_conv(const float* __restrict__ x, ushort_t* __restrict__ out_us) {
  const size_t e8 = ((size_t)blockIdx.x * 256u + threadIdx.x) * 8;   // 8 elems/thread
  const size_t row = e8 >> 9;
  const int k = (int)(e8 & 511);
  float4 v0 = *reinterpret_cast<const float4*>(x + e8);
  float4 v1 = *reinterpret_cast<const float4*>(x + e8 + 4);
  short8 s;
  s[0] = (short)f2bf(v0.x); s[1] = (short)f2bf(v0.y);
  s[2] = (short)f2bf(v0.z); s[3] = (short)f2bf(v0.w);
  s[4] = (short)f2bf(v1.x); s[5] = (short)f2bf(v1.y);
  s[6] = (short)f2bf(v1.z); s[7] = (short)f2bf(v1.w);
  *reinterpret_cast<short8*>(&out_us[(row + 1) * 1024 + k]) = s;
}

// ---------------- x-projection masked-linear GEMM (fully async staging) ----------------
// grid (12, 1024): combo = (gate p, N-tile) fastest -> one A-tile's 12 readers
// dispatch consecutively (L2/L3-hot A), M-tile slowest. 128x128 tiles.
__global__ __launch_bounds__(256, 2) void k_xgemm(
    const ushort_t* __restrict__ xbf_us, const ushort_t* __restrict__ wbf,
    ushort_t* __restrict__ xgo, ushort_t* __restrict__ xgc,
    ushort_t* __restrict__ xgf_last, ushort_t* out_xgf) {
  __shared__ ushort_t At[128][64];
  __shared__ ushort_t Bt[2][128][64];
  const int combo = blockIdx.x;
  const int p  = combo % 3;
  const int n0 = (combo / 3) * 128;
  const int R0 = blockIdx.y * 128;
  const ushort_t* Wmain = wbf + (size_t)(2 * p) * kMat;
  const ushort_t* Wmask = wbf + (size_t)(2 * p + 1) * kMat;
  const int tid = threadIdx.x;
  const int lane = tid & 63, w = tid >> 6;
  const int wr = w >> 1, wc = w & 1;

  floatx4 accM[4][4], accK[4][4];
#pragma unroll
  for (int mt = 0; mt < 4; ++mt)
#pragma unroll
    for (int nt = 0; nt < 4; ++nt) {
      accM[mt][nt] = (floatx4){0.f, 0.f, 0.f, 0.f};
      accK[mt][nt] = (floatx4){0.f, 0.f, 0.f, 0.f};
    }

  for (int kb = 0; kb < 8; ++kb) {
    __syncthreads();
    // ---- stage B via async global->LDS (width 16): wave w, call j stages
    //      8 rows r8=(j*4+w)*8; lane l -> row r8+(l>>3), col (l&7)*8 ----
#pragma unroll
    for (int m2 = 0; m2 < 2; ++m2) {
      const ushort_t* Wsrc = m2 ? Wmask : Wmain;
#pragma unroll
      for (int j = 0; j < 4; ++j) {
        const int r8 = (j * 4 + w) * 8;
        const ushort_t* g = Wsrc + (size_t)(n0 + r8 + (lane >> 3)) * 512 + kb * 64 + (lane & 7) * 8;
        __builtin_amdgcn_global_load_lds(
            (const __attribute__((address_space(1))) unsigned int*)g,
            (__attribute__((address_space(3))) unsigned int*)&Bt[m2][r8][0],
            16, 0, 0);
      }
    }
    // ---- stage A via async global->LDS: x_bf16 row r at out ushorts (r+1)*1024 ----
#pragma unroll
    for (int j = 0; j < 4; ++j) {
      const int r8 = (j * 4 + w) * 8;
      const ushort_t* g = xbf_us + (size_t)(R0 + r8 + (lane >> 3) + 1) * 1024 + kb * 64 + (lane & 7) * 8;
      __builtin_amdgcn_global_load_lds(
          (const __attribute__((address_space(1))) unsigned int*)g,
          (__attribute__((address_space(3))) unsigned int*)&At[r8][0],
          16, 0, 0);
    }
    __syncthreads();   // drains vmcnt (incl. global_load_lds) before LDS reads
#pragma unroll
    for (int ks = 0; ks < 2; ++ks) {
      const int ko = ks * 32 + (lane >> 4) * 8;
      short8 a[4], b0[4], b1[4];
#pragma unroll
      for (int mt = 0; mt < 4; ++mt)
        a[mt] = *reinterpret_cast<const short8*>(&At[wr * 64 + mt * 16 + (lane & 15)][ko]);
#pragma unroll
      for (int nt = 0; nt < 4; ++nt) {
        b0[nt] = *reinterpret_cast<const short8*>(&Bt[0][wc * 64 + nt * 16 + (lane & 15)][ko]);
        b1[nt] = *reinterpret_cast<const short8*>(&Bt[1][wc * 64 + nt * 16 + (lane & 15)][ko]);
      }
#pragma unroll
      for (int mt = 0; mt < 4; ++mt)
#pragma unroll
        for (int nt = 0; nt < 4; ++nt) {
          accM[mt][nt] = __builtin_amdgcn_mfma_f32_16x16x32_bf16(a[mt], b0[nt], accM[mt][nt], 0, 0, 0);
          accK[mt][nt] = __builtin_amdgcn_mfma_f32_16x16x32_bf16(a[mt], b1[nt], accK[mt][nt], 0, 0, 0);
        }
    }
  }
#pragma unroll
  for (int mt = 0; mt < 4; ++mt)
#pragma unroll
    for (int nt = 0; nt < 4; ++nt)
#pragma unroll
      for (int r = 0; r < 4; ++r) {
        float val = sigf(accK[mt][nt][r]) * accM[mt][nt][r];
        int row = R0 + wr * 64 + mt * 16 + (lane >> 4) * 4 + r;   // flattened b*S+t
        int col = n0 + wc * 64 + nt * 16 + (lane & 15);
        ushort_t bv = f2bf(val);
        if (p == 1) {
          xgo[(size_t)row * 512 + col] = bv;
        } else if (p == 2) {
          xgc[(size_t)row * 512 + col] = bv;
        } else {
          int t = row & 1023;
          if (t == 1023) xgf_last[(row >> 10) * 512 + col] = bv;
          else out_xgf[(size_t)(row + 1) * 1024 + 512 + col] = bv;  // ushorts [512,1024) of slot t+1
        }
      }
}

// ---------------- recurrence: persistent, 16 teams x 16 blocks, tagged exchange ----------------
__global__ __launch_bounds__(256, 1) void k_recur(
    const ushort_t* __restrict__ ubf,
    const ushort_t* __restrict__ xgo, const ushort_t* __restrict__ xgc,
    const ushort_t* __restrict__ xgf_last,
    unsigned* hbuf,
    const float* __restrict__ bfp, const float* __restrict__ bop, const float* __restrict__ bcp,
    float* out) {
  __shared__ ushort_t htile[16][520];   // rows 8..15 stay zero
  __shared__ float comb[12][8][16];
  const int bid = blockIdx.x;
  const int team = bid >> 4;     // 16 teams of 8 batch rows
  const int member = bid & 15;   // 16 blocks/team, 32 cols each
  const int tid = threadIdx.x;
  const int lane = tid & 63, w = tid >> 6;

  // ---- resident U weight fragments: wave w owns chunks {w, w+4, w+8} ----
  short8 uw[3][16];
#pragma unroll
  for (int i = 0; i < 3; ++i) {
    const int c = w + 4 * i;
    const int m = c % 6, ct = c / 6;
    const int row = member * 32 + ct * 16 + (lane & 15);
    const ushort_t* src = ubf + (size_t)m * kMat + (size_t)row * 512 + (lane >> 4) * 8;
#pragma unroll
    for (int kf = 0; kf < 16; ++kf)
      uw[i][kf] = *reinterpret_cast<const short8*>(src + kf * 32);
  }
  // keep weight values non-rematerializable (R8/R9 insurance)
#pragma unroll
  for (int i = 0; i < 3; ++i)
#pragma unroll
    for (int kf = 0; kf < 16; ++kf)
      asm volatile("" : "+v"(uw[i][kf]));

  // zero htile rows 8..15 and the pad columns once
  {
    unsigned* hrow = reinterpret_cast<unsigned*>(&htile[8 + (tid >> 5)][0]) + (tid & 31) * 8;
#pragma unroll
    for (int q = 0; q < 8; ++q) hrow[q] = 0u;
    if (tid < 64) {
      reinterpret_cast<unsigned*>(&htile[tid >> 2][512])[tid & 3] = 0u;
    }
  }

  // elementwise identity: thread -> (row er, col ej)
  const int er = tid >> 5;          // 0..7
  const int ej = tid & 31;          // 0..31
  const int ect = ej >> 4, ejj = ej & 15;
  const int col = member * 32 + ej;
  const int b = team * 8 + er;
  const float bfv = bfp[col], bov = bop[col], bcv = bcp[col];
  float cp = 0.0f;

  unsigned* hb = hbuf + (size_t)team * 8192;   // [2 phases][4096] tagged words
  const ushort_t* out_us = reinterpret_cast<const ushort_t*>(out);

  for (int t = 0; t < 1024; ++t) {
    // xg prefetch (independent of h; in flight during the sleep + poll)
    const size_t bt = (size_t)b * 1024 + t;
    const float xov = bf2f(xgo[bt * 512 + col]);
    const float xcv = bf2f(xgc[bt * 512 + col]);
    const float xfv = (t == 1023) ? bf2f(xgf_last[b * 512 + col])
                                  : bf2f(out_us[(bt + 1) * 1024 + 512 + col]);

    // ---- poll + pull h(t): 16 tagged words/thread, single rolling sweep ----
    {
      const unsigned tg = (unsigned)t & 0xFFFFu;
      const unsigned* src = hb + (size_t)(t & 1) * 4096 + tid;
      unsigned wv[16];
      // sleep ~1kcy: matches publish-store one-way commit latency (R13 win)
      if (t) __builtin_amdgcn_s_sleep(16);
#pragma unroll
      for (int q = 0; q < 16; ++q)
        wv[q] = __hip_atomic_load(src + q * 256, __ATOMIC_RELAXED, __HIP_MEMORY_SCOPE_AGENT);
      for (;;) {
        unsigned bad = 0u;
#pragma unroll
        for (int q = 0; q < 16; ++q) bad |= (wv[q] ^ tg);
        if ((bad & 0xFFFFu) == 0u) break;
        // batched re-load of stale words only (exec-masked, all outstanding together)
#pragma unroll
        for (int q = 0; q < 16; ++q)
          if ((wv[q] & 0xFFFFu) != tg)
            wv[q] = __hip_atomic_load(src + q * 256, __ATOMIC_RELAXED, __HIP_MEMORY_SCOPE_AGENT);
      }
      // stage to LDS: word (q*256+tid) -> row q>>1, col (q&1)*256+tid
#pragma unroll
      for (int q = 0; q < 16; ++q)
        htile[q >> 1][(q & 1) * 256 + tid] = (ushort_t)(wv[q] >> 16);
    }
    __syncthreads();

    // ---- A fragments from LDS ----
    short8 af[16];
    {
      const ushort_t* abase = &htile[lane & 15][(lane >> 4) * 8];
#pragma unroll
      for (int kf = 0; kf < 16; ++kf)
        af[kf] = *reinterpret_cast<const short8*>(abase + kf * 32);
    }

    floatx4 acc[3];
#pragma unroll
    for (int i = 0; i < 3; ++i) acc[i] = (floatx4){0.f, 0.f, 0.f, 0.f};
#pragma unroll
    for (int kf = 0; kf < 16; ++kf)
#pragma unroll
      for (int i = 0; i < 3; ++i)
        acc[i] = __builtin_amdgcn_mfma_f32_16x16x32_bf16(af[kf], uw[i][kf], acc[i], 0, 0, 0);

    // scatter acc rows 0..7 to LDS for the pair-combine
    if (lane < 32) {
      const int rr = (lane >> 4) * 4;
#pragma unroll
      for (int i = 0; i < 3; ++i) {
        const int c = w + 4 * i;
#pragma unroll
        for (int r = 0; r < 4; ++r) comb[c][rr + r][lane & 15] = acc[i][r];
      }
    }
    __syncthreads();

    const float hUf  = comb[ect * 6 + 0][er][ejj];
    const float hUfm = comb[ect * 6 + 1][er][ejj];
    const float hUo  = comb[ect * 6 + 2][er][ejj];
    const float hUom = comb[ect * 6 + 3][er][ejj];
    const float hUc  = comb[ect * 6 + 4][er][ejj];
    const float hUcm = comb[ect * 6 + 5][er][ejj];

    const float fg = sigf(sigf(hUfm) * hUf + xfv + bfv);
    const float og = sigf(sigf(hUom) * hUo + xov + bov);
    const float cn = fg * cp + tanhfast(sigf(hUcm) * hUc + xcv + bcv);
    const float hv = og * cn;
    cp = cn;

    // ---- publish h(t+1) first (starts propagating while we finish stores) ----
    if (t < 1023) {
      const unsigned word = ((unsigned)f2bf(hv) << 16) | ((unsigned)(t + 1) & 0xFFFFu);
      __hip_atomic_store(hb + (size_t)((t + 1) & 1) * 4096 + er * 512 + col, word,
                         __ATOMIC_RELAXED, __HIP_MEMORY_SCOPE_AGENT);
    }

    out[bt * 512 + col] = hv;                       // y (overwrites consumed xg_f slot)
    if (t == 1023) {
      out[67108864ull + (size_t)b * 512 + col] = hv;            // hT
      out[67108864ull + 65536ull + (size_t)b * 512 + col] = cn; // cT
    }
    // next iteration's LDS pull-write gated by this sync (htile reuse safe)
    __syncthreads();
  }
}

extern "C" void kernel_launch(void* const* d_in, const int* in_sizes, int n_in,
                              void* d_out, int out_size, void* d_ws, size_t ws_size,
                              hipStream_t stream) {
  (void)in_sizes; (void)n_in; (void)out_size; (void)ws_size;
  // d_in order: 0 Wf,1 Wf_m,2 Wi,3 Wi_m,4 Wo,5 Wo_m,6 Wc,7 Wc_m,
  //             8 Uf,9 Uf_m,10 Ui,11 Ui_m,12 Uo,13 Uo_m,14 Uc,15 Uc_m,
  //             16 bf,17 bi,18 bo,19 bc, 20 x
  char* ws = (char*)d_ws;
  ushort_t* wbf = (ushort_t*)(ws + O_W);
  const ushort_t* ubf = wbf + 6 * kMat;
  ushort_t* xgo = (ushort_t*)(ws + O_XGO);
  ushort_t* xgc = (ushort_t*)(ws + O_XGC);
  ushort_t* xgfl = (ushort_t*)(ws + O_XGF);
  unsigned* hbuf = (unsigned*)(ws + O_HB);

  Ptrs12 pa;
  pa.p[0] = (const float*)d_in[0];  pa.p[1] = (const float*)d_in[1];   // Wf, Wf_m
  pa.p[2] = (const float*)d_in[4];  pa.p[3] = (const float*)d_in[5];   // Wo, Wo_m
  pa.p[4] = (const float*)d_in[6];  pa.p[5] = (const float*)d_in[7];   // Wc, Wc_m
  pa.p[6] = (const float*)d_in[8];  pa.p[7] = (const float*)d_in[9];   // Uf, Uf_m
  pa.p[8] = (const float*)d_in[12]; pa.p[9] = (const float*)d_in[13];  // Uo, Uo_m
  pa.p[10] = (const float*)d_in[14]; pa.p[11] = (const float*)d_in[15]; // Uc, Uc_m

  // zero exactly hbuf's 131072 u32 after converting 3145728 weight elems
  hipLaunchKernelGGL(k_prep, dim3((12u * 262144u + 131072u) / 256u), dim3(256), 0, stream,
                     pa, wbf, hbuf);
  // x fp32 -> bf16 once, into d_out slot lower-halves
  hipLaunchKernelGGL(k_conv, dim3(32768), dim3(256), 0, stream,
                     (const float*)d_in[20], (ushort_t*)d_out);
  hipLaunchKernelGGL(k_xgemm, dim3(12, 1024), dim3(256), 0, stream,
                     (const ushort_t*)d_out, wbf, xgo, xgc, xgfl, (ushort_t*)d_out);

  const ushort_t* a_ubf = ubf;
  const ushort_t* a_xgo = xgo;
  const ushort_t* a_xgc = xgc;
  const ushort_t* a_xgfl = xgfl;
  unsigned* a_hbuf = hbuf;
  const float* a_bf = (const float*)d_in[16];
  const float* a_bo = (const float*)d_in[18];
  const float* a_bc = (const float*)d_in[19];
  float* a_out = (float*)d_out;
  void* kargs[9] = { (void*)&a_ubf, (void*)&a_xgo, (void*)&a_xgc, (void*)&a_xgfl,
                     (void*)&a_hbuf, (void*)&a_bf, (void*)&a_bo, (void*)&a_bc, (void*)&a_out };
  hipError_t ce = hipLaunchCooperativeKernel((const void*)k_recur, dim3(256), dim3(256),
                                             kargs, 0, stream);
  if (ce != hipSuccess) {
    // fallback: plain launch (256 blocks, 1 block/CU, all co-resident)
    hipLaunchKernelGGL(k_recur, dim3(256), dim3(256), 0, stream,
                       ubf, xgo, xgc, xgfl, hbuf, a_bf, a_bo, a_bc, a_out);
  }
}